// Round 12
// baseline (46.623 us; speedup 1.0000x reference)
//
#include <hip/hip_runtime.h>

// Problem constants (fixed by reference)
#define NPTS  8192
#define GXD   334
#define GYD   334
#define GZD   2
#define BATCH 2
#define NV    (BATCH * GZD * GYD * GXD)   // 446224 voxel cells
#define NVP   446464                       // padded to multiple of 256
#define KADJ  50

#define GBLK  2048    // gather: one 64-lane wave per point, 4 waves/block
#define GTHR  256
#define TGRP  16      // tail: points per thread per pass (2 passes x 16 = 32)

// ECL-CC-style find with path halving. Parent values are always smaller
// same-component members (monotone chains); stale reads at worst cause a
// CAS retry in unite(). Halving stores are hints; stale hints are older
// valid ancestors -> benign.
__device__ __forceinline__ int rep_find(int* parent, int v) {
    int curr = parent[v];
    if (curr != v) {
        int prev = v, next;
        while (curr > (next = parent[curr])) {
            parent[prev] = next;   // halving hint (benign race)
            prev = curr;
            curr = next;
        }
    }
    return curr;
}

__device__ __forceinline__ void unite(int* parent, int u, int v) {
    int ru = rep_find(parent, u);
    int rv = rep_find(parent, v);
    while (ru != rv) {
        if (ru < rv) { int t = ru; ru = rv; rv = t; }   // ru = larger
        int prev = atomicCAS(&parent[ru], ru, rv);      // device-scope RMW
        if (prev == ru) return;
        ru = rep_find(parent, prev);
        rv = rep_find(parent, rv);
    }
}

// Phase 1: dense direct-addressed voxel accumulate (dense beats hash ~11us,
// rounds 6/9 A/B). Also inits union-find and packs voxel coords for gather.
// rep encoding: atomicMax(NPTS-i) over zero-init -> decode NPTS-v = min index.
__global__ void k_accum(const float* __restrict__ pts, const int* __restrict__ bidx,
                        float* cnt, float* sx, float* sy, float* sz, int* rep,
                        int* parent, int* pvid) {
    int i = blockIdx.x * blockDim.x + threadIdx.x;
    if (i >= NPTS) return;
    parent[i] = i;
    float x = pts[3 * i + 0], y = pts[3 * i + 1], z = pts[3 * i + 2];
    // Mirror ref exactly: floor((p - PC_MIN)/VOXEL), clip after cast.
    int cx = (int)floorf((x - (-50.0f)) / 0.3f);
    int cy = (int)floorf((y - (-50.0f)) / 0.3f);
    int cz = (int)floorf((z - (-5.0f))  / 6.0f);
    cx = min(max(cx, 0), GXD - 1);
    cy = min(max(cy, 0), GYD - 1);
    cz = min(max(cz, 0), GZD - 1);
    int b = bidx[i];
    pvid[i] = cx | (cy << 9) | (cz << 18) | (b << 19);
    int vid = ((b * GZD + cz) * GYD + cy) * GXD + cx;
    atomicAdd(&cnt[vid], 1.0f);
    atomicAdd(&sx[vid], x);
    atomicAdd(&sy[vid], y);
    atomicAdd(&sz[vid], z);
    atomicMax(&rep[vid], NPTS - i);
}

// Phase 2+3: main gather identical to round-10 keeper (256-thr blocks, no LDS
// array -> resource envelope unchanged for all 2048 blocks). LAST block runs a
// register-batched pipelined root chase: 16 independent chains per thread per
// pass, fully unrolled static indexing (rule #20), agent-scope loads bypassing
// stale L1/L2. No __threadfence anywhere (round-7: ~150us in wide launches).
__global__ void __launch_bounds__(GTHR) k_gather(
        const int* __restrict__ pvid,
        const float* __restrict__ cnt, const float* __restrict__ sx,
        const float* __restrict__ sy, const float* __restrict__ sz,
        const int* __restrict__ rep,
        int* parent, int* done, float* __restrict__ out) {
    int tid  = blockIdx.x * GTHR + threadIdx.x;
    int i    = tid >> 6;          // point index
    int lane = tid & 63;

    int p  = pvid[i];             // wave-uniform single load
    int cx = p & 511, cy = (p >> 9) & 511, cz = (p >> 18) & 1, b = (p >> 19) & 1;
    int vid = ((b * GZD + cz) * GYD + cy) * GXD + cx;

    bool  occ = false;
    float ncn = 1.0f, nxc = 0.0f, nyc = 0.0f;
    int   nrep = 0;
    if (lane < KADJ) {
        int zz  = lane / 25;
        int rem = lane % 25;
        int dy  = rem / 5 - 2;
        int dx  = rem % 5 - 2;
        int ny = cy + dy, nx = cx + dx;
        if (ny >= 0 && ny < GYD && nx >= 0 && nx < GXD) {
            int nvid = ((b * GZD + zz) * GYD + ny) * GXD + nx;
            float c = cnt[nvid];
            if (c > 0.0f) {
                occ  = true;
                ncn  = fmaxf(c, 1.0f);          // ref: sums / maximum(cnt,1)
                nxc  = sx[nvid] / ncn;
                nyc  = sy[nvid] / ncn;
                nrep = NPTS - rep[nvid];        // min point index of that voxel
            }
        }
    }

    // own voxel center broadcast from the (dx=0,dy=0,zz=cz) lane
    int lane_own = cz * 25 + 12;
    float cxf    = __shfl(nxc, lane_own);
    float cyf    = __shfl(nyc, lane_own);
    float cn_own = __shfl(ncn, lane_own);

    if (occ) {
        float ddx = cxf - nxc;
        float ddy = cyf - nyc;
        // separate roundings like ref (no FMA contraction)
        float sq = __fadd_rn(__fmul_rn(ddx, ddx), __fmul_rn(ddy, ddy));
        if (sqrtf(sq) < 0.6f && nrep != i)
            unite(parent, i, nrep);
    }

    if (lane == 0) {
        // float32 outputs: cluster_inds interleaved [b,c], valid, cpp
        out[2 * i]                = (float)b;
        out[2 * NPTS + i]         = 1.0f;       // cnt >= MIN_POINTS=1 always
        out[3 * NPTS + 3 * i + 0] = cxf;
        out[3 * NPTS + 3 * i + 1] = cyf;
        out[3 * NPTS + 3 * i + 2] = sz[vid] / cn_own;
    }

    // ---- fence-free last-block handshake (validated rounds 8/11) ----
    __shared__ int isLast;
    __syncthreads();              // drains vmcnt: this block's unions performed
    if (threadIdx.x == 0)
        isLast = (atomicAdd(done, 1) == GBLK - 1);
    __syncthreads();
    if (!isLast) return;

    // Register-batched chase: 2 passes x 16 points/thread. Within a pass the
    // 16 chains are independent -> loads pipeline; total ~depth(2-3) rounds.
    for (int pass = 0; pass < 2; pass++) {
        int base = pass * (GTHR * TGRP) + threadIdx.x;   // coalesced: +k*GTHR
        int r[TGRP];
#pragma unroll
        for (int k = 0; k < TGRP; k++)
            r[k] = __hip_atomic_load(&parent[base + k * GTHR],
                                     __ATOMIC_RELAXED, __HIP_MEMORY_SCOPE_AGENT);
        bool changed = true;
        while (changed) {
            changed = false;
            int nr[TGRP];
#pragma unroll
            for (int k = 0; k < TGRP; k++)
                nr[k] = __hip_atomic_load(&parent[r[k]],
                                          __ATOMIC_RELAXED, __HIP_MEMORY_SCOPE_AGENT);
#pragma unroll
            for (int k = 0; k < TGRP; k++)
                if (nr[k] != r[k]) { r[k] = nr[k]; changed = true; }
        }
#pragma unroll
        for (int k = 0; k < TGRP; k++)
            out[2 * (base + k * GTHR) + 1] = (float)r[k];  // root == ref label
    }
}

extern "C" void kernel_launch(void* const* d_in, const int* in_sizes, int n_in,
                              void* d_out, int out_size, void* d_ws, size_t ws_size,
                              hipStream_t stream) {
    const float* pts  = (const float*)d_in[0];
    const int*   bidx = (const int*)d_in[1];
    float* out = (float*)d_out;

    char* w = (char*)d_ws;
    float* cnt    = (float*)(w + 0L * NVP * 4);
    float* sx     = (float*)(w + 1L * NVP * 4);
    float* sy     = (float*)(w + 2L * NVP * 4);
    float* sz     = (float*)(w + 3L * NVP * 4);
    int*   rep    = (int*)  (w + 4L * NVP * 4);
    int*   done   = (int*)  (w + 5L * NVP * 4 - 256);   // in rep's padding (cell
                                                        // NVP-64 > NV: never a voxel)
    int*   parent = (int*)  (w + 5L * NVP * 4);         // 8192 ints
    int*   pvid   = (int*)  (w + 5L * NVP * 4 + 32768); // 8192 ints; ws use ~9 MB

    // Zero the five dense voxel arrays + done counter (~1.4us of fill).
    hipMemsetAsync(w, 0, 5L * NVP * 4, stream);

    hipLaunchKernelGGL(k_accum, dim3(NPTS / 256), dim3(256), 0, stream,
                       pts, bidx, cnt, sx, sy, sz, rep, parent, pvid);
    hipLaunchKernelGGL(k_gather, dim3(GBLK), dim3(GTHR), 0, stream,
                       pvid, cnt, sx, sy, sz, rep, parent, done, out);
}

// Round 13
// 25.052 us; speedup vs baseline: 1.8610x; 1.8610x over previous
//
#include <hip/hip_runtime.h>

// Problem constants (fixed by reference)
#define NPTS  8192
#define GXD   334
#define GYD   334
#define GZD   2
#define BATCH 2
#define NV    (BATCH * GZD * GYD * GXD)   // 446224 voxel cells
#define NVP   446464                       // padded to multiple of 256
#define KADJ  50

#define GBLK  2048    // gather: one 64-lane wave per point, 4 waves/block
#define GTHR  256

// ECL-CC-style find with path halving. Parent values are always smaller
// same-component members (monotone chains); stale reads at worst cause a
// CAS retry in unite(). Halving stores are hints; stale hints are older
// valid ancestors -> benign.
__device__ __forceinline__ int rep_find(int* parent, int v) {
    int curr = parent[v];
    if (curr != v) {
        int prev = v, next;
        while (curr > (next = parent[curr])) {
            parent[prev] = next;   // halving hint (benign race)
            prev = curr;
            curr = next;
        }
    }
    return curr;
}

__device__ __forceinline__ void unite(int* parent, int u, int v) {
    int ru = rep_find(parent, u);
    int rv = rep_find(parent, v);
    while (ru != rv) {
        if (ru < rv) { int t = ru; ru = rv; rv = t; }   // ru = larger
        int prev = atomicCAS(&parent[ru], ru, rv);      // device-scope RMW
        if (prev == ru) return;
        ru = rep_find(parent, prev);
        rv = rep_find(parent, rv);
    }
}

// Phase 1: dense direct-addressed voxel accumulate (round-6/9 A/B verdict:
// dense beats hash by ~11us — no dependent probe chains). Also initializes
// union-find and precomputes packed voxel coords for gather.
// rep encoding: atomicMax(NPTS-i) over zero-init -> decode NPTS-v = min index.
__global__ void k_accum(const float* __restrict__ pts, const int* __restrict__ bidx,
                        float* cnt, float* sx, float* sy, float* sz, int* rep,
                        int* parent, int* pvid) {
    int i = blockIdx.x * blockDim.x + threadIdx.x;
    if (i >= NPTS) return;
    parent[i] = i;
    float x = pts[3 * i + 0], y = pts[3 * i + 1], z = pts[3 * i + 2];
    // Mirror ref exactly: floor((p - PC_MIN)/VOXEL), clip after cast.
    int cx = (int)floorf((x - (-50.0f)) / 0.3f);
    int cy = (int)floorf((y - (-50.0f)) / 0.3f);
    int cz = (int)floorf((z - (-5.0f))  / 6.0f);
    cx = min(max(cx, 0), GXD - 1);
    cy = min(max(cy, 0), GYD - 1);
    cz = min(max(cz, 0), GZD - 1);
    int b = bidx[i];
    pvid[i] = cx | (cy << 9) | (cz << 18) | (b << 19);
    int vid = ((b * GZD + cz) * GYD + cy) * GXD + cx;
    atomicAdd(&cnt[vid], 1.0f);
    atomicAdd(&sx[vid], x);
    atomicAdd(&sy[vid], y);
    atomicAdd(&sz[vid], z);
    atomicMax(&rep[vid], NPTS - i);
}

// Phase 2: one wave per point; lane < 50 owns window cell (zz,dy,dx); passing
// lanes unite(point, neighbor-voxel rep). No tail, no handshake, no fence —
// the kernel boundary is the cross-XCD release (rounds 4/5/7/8/11/12: grid.sync
// ~100us, __threadfence ~150us, fused tails +5..+21us; dispatch ~5us).
__global__ void __launch_bounds__(GTHR) k_gather(
        const int* __restrict__ pvid,
        const float* __restrict__ cnt, const float* __restrict__ sx,
        const float* __restrict__ sy, const float* __restrict__ sz,
        const int* __restrict__ rep,
        int* parent, float* __restrict__ out) {
    int tid  = blockIdx.x * GTHR + threadIdx.x;
    int i    = tid >> 6;          // point index
    int lane = tid & 63;

    int p  = pvid[i];             // wave-uniform single load
    int cx = p & 511, cy = (p >> 9) & 511, cz = (p >> 18) & 1, b = (p >> 19) & 1;
    int vid = ((b * GZD + cz) * GYD + cy) * GXD + cx;

    bool  occ = false;
    float ncn = 1.0f, nxc = 0.0f, nyc = 0.0f;
    int   nrep = 0;
    if (lane < KADJ) {
        int zz  = lane / 25;
        int rem = lane % 25;
        int dy  = rem / 5 - 2;
        int dx  = rem % 5 - 2;
        int ny = cy + dy, nx = cx + dx;
        if (ny >= 0 && ny < GYD && nx >= 0 && nx < GXD) {
            int nvid = ((b * GZD + zz) * GYD + ny) * GXD + nx;
            float c = cnt[nvid];
            if (c > 0.0f) {
                occ  = true;
                ncn  = fmaxf(c, 1.0f);          // ref: sums / maximum(cnt,1)
                nxc  = sx[nvid] / ncn;
                nyc  = sy[nvid] / ncn;
                nrep = NPTS - rep[nvid];        // min point index of that voxel
            }
        }
    }

    // own voxel center broadcast from the (dx=0,dy=0,zz=cz) lane
    int lane_own = cz * 25 + 12;
    float cxf    = __shfl(nxc, lane_own);
    float cyf    = __shfl(nyc, lane_own);
    float cn_own = __shfl(ncn, lane_own);

    if (occ) {
        float ddx = cxf - nxc;
        float ddy = cyf - nyc;
        // separate roundings like ref (no FMA contraction)
        float sq = __fadd_rn(__fmul_rn(ddx, ddx), __fmul_rn(ddy, ddy));
        if (sqrtf(sq) < 0.6f && nrep != i)
            unite(parent, i, nrep);
    }

    if (lane == 0) {
        // float32 outputs: cluster_inds interleaved [b,c], valid, cpp
        out[2 * i]                = (float)b;
        out[2 * NPTS + i]         = 1.0f;       // cnt >= MIN_POINTS=1 always
        out[3 * NPTS + 3 * i + 0] = cxf;
        out[3 * NPTS + 3 * i + 1] = cyf;
        out[3 * NPTS + 3 * i + 2] = sz[vid] / cn_own;
    }
}

// Phase 3: labels = component root (== min point index == ref label).
// Separate dispatch => all unions device-visible; plain cached loads suffice
// (dispatch-start acquire), parent is 32KB -> L2-resident chases.
__global__ void k_final(const int* __restrict__ parent, float* __restrict__ out) {
    int i = blockIdx.x * blockDim.x + threadIdx.x;
    if (i >= NPTS) return;
    int r = parent[i];
    for (;;) {
        int rr = parent[r];
        if (rr == r) break;
        r = rr;
    }
    out[2 * i + 1] = (float)r;
}

extern "C" void kernel_launch(void* const* d_in, const int* in_sizes, int n_in,
                              void* d_out, int out_size, void* d_ws, size_t ws_size,
                              hipStream_t stream) {
    const float* pts  = (const float*)d_in[0];
    const int*   bidx = (const int*)d_in[1];
    float* out = (float*)d_out;

    char* w = (char*)d_ws;
    float* cnt    = (float*)(w + 0L * NVP * 4);
    float* sx     = (float*)(w + 1L * NVP * 4);
    float* sy     = (float*)(w + 2L * NVP * 4);
    float* sz     = (float*)(w + 3L * NVP * 4);
    int*   rep    = (int*)  (w + 4L * NVP * 4);
    int*   parent = (int*)  (w + 5L * NVP * 4);            // 8192 ints
    int*   pvid   = (int*)  (w + 5L * NVP * 4 + 32768);    // 8192 ints
    // ws use ~9 MB

    // Zero the five dense voxel arrays (cnt/sx/sy/sz/rep): ~1.3us of fill.
    hipMemsetAsync(w, 0, 5L * NVP * 4, stream);

    hipLaunchKernelGGL(k_accum, dim3(NPTS / 256), dim3(256), 0, stream,
                       pts, bidx, cnt, sx, sy, sz, rep, parent, pvid);
    hipLaunchKernelGGL(k_gather, dim3(GBLK), dim3(GTHR), 0, stream,
                       pvid, cnt, sx, sy, sz, rep, parent, out);
    hipLaunchKernelGGL(k_final, dim3(NPTS / 256), dim3(256), 0, stream,
                       parent, out);
}